// Round 1
// baseline (25758.994 us; speedup 1.0000x reference)
//
#include <hip/hip_runtime.h>
#include <math.h>

// Problem dims
#define Bb 256
#define Ii 128
#define Tt 256
#define Hh 512
#define Oo 2
#define TBr (Tt*Bb)      // 65536 time-major rows
#define EPS_BN 1e-5f

// GEMM tiles
#define TM 32
#define TN 64
#define TK 16

__device__ __forceinline__ float sigmoidf_(float x) { return 1.f / (1.f + expf(-x)); }
__device__ __forceinline__ float softplusf_(float x) { return fmaxf(x, 0.f) + log1pf(expf(-fabsf(x))); }

// ---------------------------------------------------------------------------
// P1: repack input [B,3,I,T] -> time-major [T*B, I] for X, M, D (LDS transpose)
// ---------------------------------------------------------------------------
__global__ __launch_bounds__(1024) void repack_kernel(const float* __restrict__ in,
                                                      float* __restrict__ Xall,
                                                      float* __restrict__ Mall,
                                                      float* __restrict__ Dall)
{
    __shared__ float tile[32][33];
    const int bz = blockIdx.z;            // b*3 + c
    const int b = bz / 3, c = bz % 3;
    const int t0 = blockIdx.x * 32, i0 = blockIdx.y * 32;
    const int tx = threadIdx.x, ty = threadIdx.y;
    const float* src = in + ((size_t)b*3 + c) * (size_t)Ii * Tt;
    tile[ty][tx] = src[(size_t)(i0 + ty)*Tt + t0 + tx];
    __syncthreads();
    float* dst = (c == 0) ? Xall : ((c == 1) ? Mall : Dall);
    dst[((size_t)(t0 + ty)*Bb + b)*Ii + i0 + tx] = tile[tx][ty];
}

// ---------------------------------------------------------------------------
// P2: pack concatenated weights
// Wcat1 [768][1024] = [Wxz|Wxr ; Wmz|Wmr ; Whz|Whr], bias1[1024] = [bz|br]
// Wcat2 [768][512]  = [Wxh ; Wmh ; Whh]
// ---------------------------------------------------------------------------
__global__ __launch_bounds__(256) void pack_weights_kernel(
    const float* __restrict__ W_xz, const float* __restrict__ W_hz, const float* __restrict__ W_mz, const float* __restrict__ b_z,
    const float* __restrict__ W_xr, const float* __restrict__ W_hr, const float* __restrict__ W_mr, const float* __restrict__ b_r,
    const float* __restrict__ W_xh, const float* __restrict__ W_hh, const float* __restrict__ W_mh,
    float* __restrict__ Wcat1, float* __restrict__ Wcat2, float* __restrict__ bias1)
{
    const int idx = blockIdx.x * blockDim.x + threadIdx.x;
    const int n1 = 768 * 1024, n2 = 768 * 512;
    if (idx < n1) {
        const int k = idx >> 10, n = idx & 1023;
        const int col = (n < Hh) ? n : (n - Hh);
        const float* Wx = (n < Hh) ? W_xz : W_xr;
        const float* Wm = (n < Hh) ? W_mz : W_mr;
        const float* Wh = (n < Hh) ? W_hz : W_hr;
        float v;
        if (k < Ii)           v = Wx[k*Hh + col];
        else if (k < 2*Ii)    v = Wm[(k - Ii)*Hh + col];
        else                  v = Wh[(k - 2*Ii)*Hh + col];
        Wcat1[idx] = v;
    } else if (idx < n1 + n2) {
        const int j = idx - n1;
        const int k = j >> 9, n = j & 511;
        float v;
        if (k < Ii)           v = W_xh[k*Hh + n];
        else if (k < 2*Ii)    v = W_mh[(k - Ii)*Hh + n];
        else                  v = W_hh[(k - 2*Ii)*Hh + n];
        Wcat2[j] = v;
    } else if (idx < n1 + n2 + 1024) {
        const int n = idx - n1 - n2;
        bias1[n] = (n < Hh) ? b_z[n] : b_r[n - Hh];
    }
}

// ---------------------------------------------------------------------------
// P5: x_last scan + x_eff, in place over Xall. Thread per (b,i), loop over t.
// ---------------------------------------------------------------------------
__global__ __launch_bounds__(256) void xeff_scan_kernel(float* __restrict__ Xall,
                                                        const float* __restrict__ Mall,
                                                        const float* __restrict__ Gx,
                                                        const float* __restrict__ xmean_p)
{
    const int bi = blockIdx.x * blockDim.x + threadIdx.x;   // b*I + i
    if (bi >= Bb * Ii) return;
    const float xm = xmean_p[0];
    float xl = 0.f;
    for (int t = 0; t < Tt; ++t) {
        const size_t off = (size_t)t * Bb * Ii + bi;
        const float x = Xall[off], m = Mall[off], gx = Gx[off];
        if (m > 0.f) xl = x;
        Xall[off] = m * x + (1.f - m) * (gx * xl + (1.f - gx) * xm);
    }
}

// ---------------------------------------------------------------------------
// Generic fp32 GEMM, 32x64 tile, 256 threads, 2x4 micro-tile.
// MODE 0: C = exp(-relu(A @ Wt + bias))                        (Gx / Gh precompute)
// MODE 2: ZR = sigmoid([Xe|Ma|Gh*Hs] @ Wt + bias); RH = r*Gh*Hs; zero stats
// MODE 3: Hraw = (1-z)*Gh*Hs + z*tanh([Xe|Ma|RH] @ Wt + bh);  atomic BN partials
// ---------------------------------------------------------------------------
template <int MODE>
__global__ __launch_bounds__(256) void gemm_kernel(
    const float* __restrict__ A, const float* __restrict__ Wt,
    const float* __restrict__ bias, float* __restrict__ C,
    const float* __restrict__ Xe, const float* __restrict__ Ma,
    const float* __restrict__ Gh, const float* __restrict__ Hs,
    const float* __restrict__ RH,
    float* __restrict__ ZR, float* __restrict__ RHout,
    float* __restrict__ Hraw, float* __restrict__ Ssum, float* __restrict__ Ssq,
    const float* __restrict__ bh,
    int M, int N, int K, int t)
{
    __shared__ float As[TK][TM + 1];
    __shared__ float Bs[TK][TN];
    const int tid = threadIdx.x;
    const int bm = blockIdx.x * TM;
    const int bn = blockIdx.y * TN;
    const int tx = tid & 15;          // col group: cols tx*4 .. +3
    const int ty = tid >> 4;          // row group: rows ty*2, ty*2+1
    float acc[2][4] = {{0.f,0.f,0.f,0.f},{0.f,0.f,0.f,0.f}};

    if (MODE == 2 && blockIdx.x == 0 && blockIdx.y == 0) {
        for (int i = tid; i < Hh; i += 256) { Ssum[i] = 0.f; Ssq[i] = 0.f; }
    }

    const int a_m = tid >> 3;         // 0..31
    const int a_k = (tid & 7) * 2;    // 0,2,..,14
    const int b_k = tid >> 4;         // 0..15
    const int b_n = (tid & 15) * 4;

    for (int k0 = 0; k0 < K; k0 += TK) {
        // --- A tile (virtual concat for per-step modes) ---
        {
            const int gm = bm + a_m;
            const int k = k0 + a_k;
            float v0, v1;
            if (MODE == 0) {
                const float* p = A + (size_t)gm * K + k;
                v0 = p[0]; v1 = p[1];
            } else {
                if (k < Ii) {
                    const float* p = Xe + ((size_t)t * Bb + gm) * Ii + k;
                    v0 = p[0]; v1 = p[1];
                } else if (k < 2 * Ii) {
                    const float* p = Ma + ((size_t)t * Bb + gm) * Ii + (k - Ii);
                    v0 = p[0]; v1 = p[1];
                } else {
                    const int n = k - 2 * Ii;
                    if (MODE == 2) {
                        const float* ph = Hs + (size_t)gm * Hh + n;
                        const float* pg = Gh + ((size_t)t * Bb + gm) * Hh + n;
                        v0 = ph[0] * pg[0]; v1 = ph[1] * pg[1];
                    } else {
                        const float* p = RH + (size_t)gm * Hh + n;
                        v0 = p[0]; v1 = p[1];
                    }
                }
            }
            As[a_k][a_m] = v0; As[a_k + 1][a_m] = v1;
        }
        // --- B tile ---
        {
            const float4 w4 = *(const float4*)(Wt + (size_t)(k0 + b_k) * N + bn + b_n);
            Bs[b_k][b_n + 0] = w4.x; Bs[b_k][b_n + 1] = w4.y;
            Bs[b_k][b_n + 2] = w4.z; Bs[b_k][b_n + 3] = w4.w;
        }
        __syncthreads();
        #pragma unroll
        for (int kk = 0; kk < TK; ++kk) {
            const float a0 = As[kk][ty * 2 + 0], a1 = As[kk][ty * 2 + 1];
            const float b0 = Bs[kk][tx * 4 + 0], b1 = Bs[kk][tx * 4 + 1];
            const float b2 = Bs[kk][tx * 4 + 2], b3 = Bs[kk][tx * 4 + 3];
            acc[0][0] += a0 * b0; acc[0][1] += a0 * b1; acc[0][2] += a0 * b2; acc[0][3] += a0 * b3;
            acc[1][0] += a1 * b0; acc[1][1] += a1 * b1; acc[1][2] += a1 * b2; acc[1][3] += a1 * b3;
        }
        __syncthreads();
    }

    if (MODE == 0) {
        #pragma unroll
        for (int i = 0; i < 2; ++i) {
            const int gm = bm + ty * 2 + i;
            #pragma unroll
            for (int j = 0; j < 4; ++j) {
                const int gn = bn + tx * 4 + j;
                const float v = acc[i][j] + bias[gn];
                C[(size_t)gm * N + gn] = expf(-fmaxf(v, 0.f));
            }
        }
    } else if (MODE == 2) {
        #pragma unroll
        for (int i = 0; i < 2; ++i) {
            const int gb = bm + ty * 2 + i;
            #pragma unroll
            for (int j = 0; j < 4; ++j) {
                const int gn = bn + tx * 4 + j;
                const float v = sigmoidf_(acc[i][j] + bias[gn]);
                ZR[(size_t)gb * 1024 + gn] = v;
                if (gn >= Hh) {
                    const int n = gn - Hh;
                    RHout[(size_t)gb * Hh + n] =
                        v * Gh[((size_t)t * Bb + gb) * Hh + n] * Hs[(size_t)gb * Hh + n];
                }
            }
        }
    } else { // MODE 3
        float sp[4] = {0.f,0.f,0.f,0.f}, sq[4] = {0.f,0.f,0.f,0.f};
        #pragma unroll
        for (int i = 0; i < 2; ++i) {
            const int gb = bm + ty * 2 + i;
            #pragma unroll
            for (int j = 0; j < 4; ++j) {
                const int gn = bn + tx * 4 + j;
                const float pre = acc[i][j] + bh[gn];
                const float z = ZR[(size_t)gb * 1024 + gn];
                const float hp = Gh[((size_t)t * Bb + gb) * Hh + gn] * Hs[(size_t)gb * Hh + gn];
                const float hr = (1.f - z) * hp + z * tanhf(pre);
                Hraw[(size_t)gb * Hh + gn] = hr;
                sp[j] += hr; sq[j] += hr * hr;
            }
        }
        __syncthreads();   // As/Bs now free; reuse Bs[16][64] for reduction
        #pragma unroll
        for (int j = 0; j < 4; ++j) Bs[ty][tx * 4 + j] = sp[j];
        __syncthreads();
        if (tid < TN) {
            float s = 0.f;
            #pragma unroll
            for (int k = 0; k < 16; ++k) s += Bs[k][tid];
            atomicAdd(&Ssum[bn + tid], s);
        }
        __syncthreads();
        #pragma unroll
        for (int j = 0; j < 4; ++j) Bs[ty][tx * 4 + j] = sq[j];
        __syncthreads();
        if (tid < TN) {
            float s = 0.f;
            #pragma unroll
            for (int k = 0; k < 16; ++k) s += Bs[k][tid];
            atomicAdd(&Ssq[bn + tid], s);
        }
    }
}

// ---------------------------------------------------------------------------
// K4: BatchNorm (batch stats) + write hs + y = softplus(h @ W_hy + b_hy)
// One block per batch row b.
// ---------------------------------------------------------------------------
__global__ __launch_bounds__(256) void bn_y_kernel(
    const float* __restrict__ Hraw, const float* __restrict__ Ssum, const float* __restrict__ Ssq,
    const float* __restrict__ gamma, const float* __restrict__ beta,
    const float* __restrict__ Why, const float* __restrict__ bhy,
    float* __restrict__ h_state, float* __restrict__ out_hs, float* __restrict__ out_ys, int t)
{
    const int b = blockIdx.x, tid = threadIdx.x;
    __shared__ float red[256];
    __shared__ float yy0;
    float p0 = 0.f, p1 = 0.f;
    #pragma unroll
    for (int c = 0; c < 2; ++c) {
        const int n = tid + c * 256;
        const float mu = Ssum[n] * (1.f / Bb);
        const float var = Ssq[n] * (1.f / Bb) - mu * mu;
        const float rstd = rsqrtf(fmaxf(var, 0.f) + EPS_BN);
        const float hr = Hraw[(size_t)b * Hh + n];
        const float ho = gamma[n] * (hr - mu) * rstd + beta[n];
        h_state[(size_t)b * Hh + n] = ho;
        out_hs[((size_t)b * Tt + t) * Hh + n] = ho;
        p0 += ho * Why[n * 2 + 0];
        p1 += ho * Why[n * 2 + 1];
    }
    red[tid] = p0; __syncthreads();
    for (int s = 128; s > 0; s >>= 1) { if (tid < s) red[tid] += red[tid + s]; __syncthreads(); }
    if (tid == 0) yy0 = red[0];
    __syncthreads();
    red[tid] = p1; __syncthreads();
    for (int s = 128; s > 0; s >>= 1) { if (tid < s) red[tid] += red[tid + s]; __syncthreads(); }
    if (tid == 0) {
        const float x0 = yy0 + bhy[0];
        const float x1 = red[0] + bhy[1];
        out_ys[((size_t)b * Tt + t) * Oo + 0] = softplusf_(x0);
        out_ys[((size_t)b * Tt + t) * Oo + 1] = softplusf_(x1);
    }
}

// ---------------------------------------------------------------------------
extern "C" void kernel_launch(void* const* d_in, const int* in_sizes, int n_in,
                              void* d_out, int out_size, void* d_ws, size_t ws_size,
                              hipStream_t stream)
{
    const float* input  = (const float*)d_in[0];
    const float* xmean  = (const float*)d_in[1];
    const float* W_dg_x = (const float*)d_in[2];
    const float* b_dg_x = (const float*)d_in[3];
    const float* W_dg_h = (const float*)d_in[4];
    const float* b_dg_h = (const float*)d_in[5];
    const float* W_xz   = (const float*)d_in[6];
    const float* W_hz   = (const float*)d_in[7];
    const float* W_mz   = (const float*)d_in[8];
    const float* b_z    = (const float*)d_in[9];
    const float* W_xr   = (const float*)d_in[10];
    const float* W_hr   = (const float*)d_in[11];
    const float* W_mr   = (const float*)d_in[12];
    const float* b_r    = (const float*)d_in[13];
    const float* W_xh   = (const float*)d_in[14];
    const float* W_hh   = (const float*)d_in[15];
    const float* W_mh   = (const float*)d_in[16];
    const float* b_h    = (const float*)d_in[17];
    const float* W_hy   = (const float*)d_in[18];
    const float* b_hy   = (const float*)d_in[19];
    const float* bn_g   = (const float*)d_in[20];
    const float* bn_b   = (const float*)d_in[21];

    float* out_ys = (float*)d_out;
    float* out_hs = out_ys + (size_t)Bb * Tt * Oo;

    float* w = (float*)d_ws;
    float* Xall  = w; w += (size_t)TBr * Ii;     // x_eff in place after scan
    float* Mall  = w; w += (size_t)TBr * Ii;
    float* Dall  = w; w += (size_t)TBr * Ii;
    float* Gx    = w; w += (size_t)TBr * Ii;
    float* Gh    = w; w += (size_t)TBr * Hh;
    float* Wcat1 = w; w += 768 * 1024;
    float* Wcat2 = w; w += 768 * 512;
    float* bias1 = w; w += 1024;
    float* ZR    = w; w += (size_t)Bb * 1024;
    float* RH    = w; w += (size_t)Bb * Hh;
    float* Hraw  = w; w += (size_t)Bb * Hh;
    float* hst   = w; w += (size_t)Bb * Hh;
    float* Ssum  = w; w += Hh;
    float* Ssq   = w; w += Hh;

    hipMemsetAsync(hst, 0, (size_t)Bb * Hh * sizeof(float), stream);

    repack_kernel<<<dim3(Tt / 32, Ii / 32, Bb * 3), dim3(32, 32), 0, stream>>>(input, Xall, Mall, Dall);

    pack_weights_kernel<<<4612, 256, 0, stream>>>(W_xz, W_hz, W_mz, b_z,
                                                  W_xr, W_hr, W_mr, b_r,
                                                  W_xh, W_hh, W_mh,
                                                  Wcat1, Wcat2, bias1);

    // Gx = exp(-relu(D @ W_dg_x + b_dg_x))   [TB, I]
    gemm_kernel<0><<<dim3(TBr / TM, Ii / TN), 256, 0, stream>>>(
        Dall, W_dg_x, b_dg_x, Gx,
        nullptr, nullptr, nullptr, nullptr, nullptr,
        nullptr, nullptr, nullptr, nullptr, nullptr, nullptr,
        TBr, Ii, Ii, 0);

    // Gh = exp(-relu(D @ W_dg_h + b_dg_h))   [TB, H]
    gemm_kernel<0><<<dim3(TBr / TM, Hh / TN), 256, 0, stream>>>(
        Dall, W_dg_h, b_dg_h, Gh,
        nullptr, nullptr, nullptr, nullptr, nullptr,
        nullptr, nullptr, nullptr, nullptr, nullptr, nullptr,
        TBr, Hh, Ii, 0);

    // x_last scan -> x_eff (in place over Xall)
    xeff_scan_kernel<<<(Bb * Ii) / 256, 256, 0, stream>>>(Xall, Mall, Gx, xmean);

    for (int t = 0; t < Tt; ++t) {
        // K1: z/r gates + RH, zero BN stats
        gemm_kernel<2><<<dim3(Bb / TM, 1024 / TN), 256, 0, stream>>>(
            nullptr, Wcat1, bias1, nullptr,
            Xall, Mall, Gh, hst, nullptr,
            ZR, RH, nullptr, Ssum, Ssq, nullptr,
            Bb, 1024, 768, t);
        // K3: h_raw + BN partial sums
        gemm_kernel<3><<<dim3(Bb / TM, Hh / TN), 256, 0, stream>>>(
            nullptr, Wcat2, nullptr, nullptr,
            Xall, Mall, Gh, hst, RH,
            ZR, nullptr, Hraw, Ssum, Ssq, b_h,
            Bb, Hh, 768, t);
        // K4: BN + hs + ys
        bn_y_kernel<<<Bb, 256, 0, stream>>>(Hraw, Ssum, Ssq, bn_g, bn_b,
                                            W_hy, b_hy, hst, out_hs, out_ys, t);
    }
}

// Round 2
// 5457.425 us; speedup vs baseline: 4.7200x; 4.7200x over previous
//
#include <hip/hip_runtime.h>
#include <math.h>

#define Bb 256
#define Ii 128
#define Tt 256
#define Hh 512
#define Oo 2
#define TBr (Tt*Bb)
#define EPS_BN 1e-5f

typedef __attribute__((ext_vector_type(8))) short short8;
typedef __attribute__((ext_vector_type(8))) __bf16 bf16x8;
typedef __attribute__((ext_vector_type(4))) float f32x4;

__device__ __forceinline__ f32x4 mfma_bf16(short8 a, short8 b, f32x4 c) {
    return __builtin_amdgcn_mfma_f32_16x16x32_bf16(
        __builtin_bit_cast(bf16x8, a), __builtin_bit_cast(bf16x8, b), c, 0, 0, 0);
}
__device__ __forceinline__ short f2bf(float f) {
    union { float f; unsigned u; } v; v.f = f;
    unsigned r = (v.u + 0x7FFFu + ((v.u >> 16) & 1u)) >> 16;
    return (short)r;
}
__device__ __forceinline__ float bf2f(short s) {
    union { unsigned u; float f; } v; v.u = ((unsigned)(unsigned short)s) << 16;
    return v.f;
}
__device__ __forceinline__ float sigmoidf_(float x) { return 1.f / (1.f + expf(-x)); }
__device__ __forceinline__ float softplusf_(float x) { return fmaxf(x, 0.f) + log1pf(expf(-fabsf(x))); }

// ---------------------------------------------------------------------------
// repack: input [B,3,I,T] fp32 -> time-major X fp32 [T,B,I], M bf16, D bf16
// ---------------------------------------------------------------------------
__global__ __launch_bounds__(1024) void repack_kernel(const float* __restrict__ in,
                                                      float* __restrict__ Xall,
                                                      short* __restrict__ Mall,
                                                      short* __restrict__ Dall)
{
    __shared__ float tile[32][33];
    const int bz = blockIdx.z;
    const int b = bz / 3, cch = bz % 3;
    const int t0 = blockIdx.x * 32, i0 = blockIdx.y * 32;
    const int tx = threadIdx.x, ty = threadIdx.y;
    const float* src = in + ((size_t)b * 3 + cch) * (size_t)Ii * Tt;
    tile[ty][tx] = src[(size_t)(i0 + ty) * Tt + t0 + tx];
    __syncthreads();
    const float v = tile[tx][ty];
    const size_t off = ((size_t)(t0 + ty) * Bb + b) * Ii + i0 + tx;
    if (cch == 0)      Xall[off] = v;
    else if (cch == 1) Mall[off] = f2bf(v);
    else               Dall[off] = f2bf(v);
}

// ---------------------------------------------------------------------------
// pack weights -> bf16 transposed (n-major rows of length K) for MFMA B frags
// Wc1T [1024][768]  (z|r), Wc2T [512][768] (h), WdgxT [128][128],
// WdghT [512][128], bias1 fp32 [1024]
// ---------------------------------------------------------------------------
__global__ __launch_bounds__(256) void pack_weights_kernel(
    const float* __restrict__ W_dg_x, const float* __restrict__ W_dg_h,
    const float* __restrict__ W_xz, const float* __restrict__ W_hz, const float* __restrict__ W_mz, const float* __restrict__ b_z,
    const float* __restrict__ W_xr, const float* __restrict__ W_hr, const float* __restrict__ W_mr, const float* __restrict__ b_r,
    const float* __restrict__ W_xh, const float* __restrict__ W_hh, const float* __restrict__ W_mh,
    short* __restrict__ Wc1T, short* __restrict__ Wc2T,
    short* __restrict__ WdgxT, short* __restrict__ WdghT, float* __restrict__ bias1)
{
    const int idx = blockIdx.x * blockDim.x + threadIdx.x;
    const int n1 = 1024 * 768, n2 = 512 * 768, n3 = 128 * 128, n4 = 512 * 128;
    if (idx < n1) {
        const int n = idx / 768, k = idx % 768;
        const int col = (n < Hh) ? n : (n - Hh);
        const float* Wx = (n < Hh) ? W_xz : W_xr;
        const float* Wm = (n < Hh) ? W_mz : W_mr;
        const float* Wh = (n < Hh) ? W_hz : W_hr;
        float v;
        if (k < Ii)        v = Wx[(size_t)k * Hh + col];
        else if (k < 2*Ii) v = Wm[(size_t)(k - Ii) * Hh + col];
        else               v = Wh[(size_t)(k - 2*Ii) * Hh + col];
        Wc1T[idx] = f2bf(v);
    } else if (idx < n1 + n2) {
        const int j = idx - n1;
        const int n = j / 768, k = j % 768;
        float v;
        if (k < Ii)        v = W_xh[(size_t)k * Hh + n];
        else if (k < 2*Ii) v = W_mh[(size_t)(k - Ii) * Hh + n];
        else               v = W_hh[(size_t)(k - 2*Ii) * Hh + n];
        Wc2T[j] = f2bf(v);
    } else if (idx < n1 + n2 + n3) {
        const int j = idx - n1 - n2;
        const int n = j >> 7, k = j & 127;
        WdgxT[j] = f2bf(W_dg_x[(size_t)k * Ii + n]);
    } else if (idx < n1 + n2 + n3 + n4) {
        const int j = idx - n1 - n2 - n3;
        const int n = j >> 7, k = j & 127;
        WdghT[j] = f2bf(W_dg_h[(size_t)k * Hh + n]);
    } else if (idx < n1 + n2 + n3 + n4 + 1024) {
        const int n = idx - n1 - n2 - n3 - n4;
        bias1[n] = (n < Hh) ? b_z[n] : b_r[n - Hh];
    }
}

// ---------------------------------------------------------------------------
// gdecay: C = bf16(exp(-relu(A @ B + bias)))  A bf16 [M][128], BT bf16 [N][128]
// one wave per block, tile 32(M) x 64(N), K=128
// ---------------------------------------------------------------------------
__global__ __launch_bounds__(64) void gdecay_kernel(const short* __restrict__ A,
                                                    const short* __restrict__ BT,
                                                    const float* __restrict__ bias,
                                                    short* __restrict__ C, int N)
{
    const int lane = threadIdx.x;
    const int c = lane & 15, g = lane >> 4;
    const int m0 = blockIdx.x * 32, n0 = blockIdx.y * 64;
    const short* a0 = A + (size_t)(m0 + c) * Ii + 8 * g;
    const short* a1 = a0 + (size_t)16 * Ii;
    const short* bw = BT + (size_t)(n0 + c) * Ii + 8 * g;
    f32x4 acc[2][4];
    #pragma unroll
    for (int i = 0; i < 2; ++i)
        #pragma unroll
        for (int f = 0; f < 4; ++f) acc[i][f] = (f32x4){0.f, 0.f, 0.f, 0.f};
    #pragma unroll
    for (int k0 = 0; k0 < 128; k0 += 32) {
        const short8 av0 = *(const short8*)(a0 + k0);
        const short8 av1 = *(const short8*)(a1 + k0);
        #pragma unroll
        for (int fn = 0; fn < 4; ++fn) {
            const short8 bv = *(const short8*)(bw + (size_t)fn * 16 * Ii + k0);
            acc[0][fn] = mfma_bf16(av0, bv, acc[0][fn]);
            acc[1][fn] = mfma_bf16(av1, bv, acc[1][fn]);
        }
    }
    #pragma unroll
    for (int fn = 0; fn < 4; ++fn) {
        const int n = n0 + fn * 16 + c;
        const float bs = bias[n];
        #pragma unroll
        for (int fm = 0; fm < 2; ++fm) {
            #pragma unroll
            for (int j = 0; j < 4; ++j) {
                const int m = m0 + fm * 16 + 4 * g + j;
                const float v = expf(-fmaxf(acc[fm][fn][j] + bs, 0.f));
                C[(size_t)m * N + n] = f2bf(v);
            }
        }
    }
}

// ---------------------------------------------------------------------------
// x_last scan + x_eff -> Xe bf16 [T,B,I]
// ---------------------------------------------------------------------------
__global__ __launch_bounds__(256) void xeff_scan_kernel(const float* __restrict__ Xall,
                                                        const short* __restrict__ Mall,
                                                        const short* __restrict__ Gx,
                                                        const float* __restrict__ xmean_p,
                                                        short* __restrict__ Xe)
{
    const int bi = blockIdx.x * blockDim.x + threadIdx.x;
    if (bi >= Bb * Ii) return;
    const float xm = xmean_p[0];
    float xl = 0.f;
    for (int t = 0; t < Tt; ++t) {
        const size_t off = (size_t)t * Bb * Ii + bi;
        const float x = Xall[off];
        const float m = bf2f(Mall[off]);
        const float gx = bf2f(Gx[off]);
        if (m > 0.f) xl = x;
        Xe[off] = f2bf(m * x + (1.f - m) * (gx * xl + (1.f - gx) * xm));
    }
}

// ---------------------------------------------------------------------------
// K1: ZR = sigmoid([Xe|M|Hp] @ Wc1 + bias1)  M=256 N=1024 K=768
//     z (n<512) -> Zbuf fp32 ; r (n>=512) -> RH = bf16(r * Hp)
//     block = 1 wave, tile 16x64, grid (16,16). Block (0,0) zeroes BN stats.
// ---------------------------------------------------------------------------
__global__ __launch_bounds__(64) void step_zr_kernel(
    const short* __restrict__ Xe, const short* __restrict__ Ma,
    const short* __restrict__ Hp, const short* __restrict__ Wc1T,
    const float* __restrict__ bias1,
    float* __restrict__ Zbuf, short* __restrict__ RH,
    float* __restrict__ Ssum, float* __restrict__ Ssq, int t)
{
    const int lane = threadIdx.x;
    const int c = lane & 15, g = lane >> 4;
    const int m0 = blockIdx.x * 16, n0 = blockIdx.y * 64;
    if (blockIdx.x == 0 && blockIdx.y == 0) {
        #pragma unroll
        for (int i = 0; i < 8; ++i) { Ssum[lane + i * 64] = 0.f; Ssq[lane + i * 64] = 0.f; }
    }
    const short* ax = Xe + ((size_t)t * Bb + m0 + c) * Ii + 8 * g;
    const short* am = Ma + ((size_t)t * Bb + m0 + c) * Ii + 8 * g;
    const short* ah = Hp + (size_t)(m0 + c) * Hh + 8 * g;
    const short* bw = Wc1T + (size_t)(n0 + c) * 768 + 8 * g;
    f32x4 acc[4];
    #pragma unroll
    for (int f = 0; f < 4; ++f) acc[f] = (f32x4){0.f, 0.f, 0.f, 0.f};
    #pragma unroll
    for (int k0 = 0; k0 < 128; k0 += 32) {
        const short8 a = *(const short8*)(ax + k0);
        #pragma unroll
        for (int fn = 0; fn < 4; ++fn) {
            const short8 b = *(const short8*)(bw + (size_t)fn * 16 * 768 + k0);
            acc[fn] = mfma_bf16(a, b, acc[fn]);
        }
    }
    #pragma unroll
    for (int k0 = 0; k0 < 128; k0 += 32) {
        const short8 a = *(const short8*)(am + k0);
        #pragma unroll
        for (int fn = 0; fn < 4; ++fn) {
            const short8 b = *(const short8*)(bw + (size_t)fn * 16 * 768 + 128 + k0);
            acc[fn] = mfma_bf16(a, b, acc[fn]);
        }
    }
    #pragma unroll
    for (int k0 = 0; k0 < 512; k0 += 32) {
        const short8 a = *(const short8*)(ah + k0);
        #pragma unroll
        for (int fn = 0; fn < 4; ++fn) {
            const short8 b = *(const short8*)(bw + (size_t)fn * 16 * 768 + 256 + k0);
            acc[fn] = mfma_bf16(a, b, acc[fn]);
        }
    }
    #pragma unroll
    for (int fn = 0; fn < 4; ++fn) {
        const int n = n0 + fn * 16 + c;
        const float bs = bias1[n];
        #pragma unroll
        for (int j = 0; j < 4; ++j) {
            const int m = m0 + 4 * g + j;
            const float v = sigmoidf_(acc[fn][j] + bs);
            if (n < Hh) {
                Zbuf[(size_t)m * Hh + n] = v;
            } else {
                const int nn = n - Hh;
                const float hp = bf2f(Hp[(size_t)m * Hh + nn]);
                RH[(size_t)m * Hh + nn] = f2bf(v * hp);
            }
        }
    }
}

// ---------------------------------------------------------------------------
// K3: pre = [Xe|M|RH] @ Wc2 + b_h ; hr = (1-z)*Hp + z*tanh(pre)
//     Hraw fp32; BN partial sums via shfl-reduce + atomics.
//     block = 1 wave, tile 16x64, grid (16,8).
// ---------------------------------------------------------------------------
__global__ __launch_bounds__(64) void step_h_kernel(
    const short* __restrict__ Xe, const short* __restrict__ Ma,
    const short* __restrict__ RH, const short* __restrict__ Hp,
    const short* __restrict__ Wc2T, const float* __restrict__ b_h,
    const float* __restrict__ Zbuf, float* __restrict__ Hraw,
    float* __restrict__ Ssum, float* __restrict__ Ssq, int t)
{
    const int lane = threadIdx.x;
    const int c = lane & 15, g = lane >> 4;
    const int m0 = blockIdx.x * 16, n0 = blockIdx.y * 64;
    const short* ax = Xe + ((size_t)t * Bb + m0 + c) * Ii + 8 * g;
    const short* am = Ma + ((size_t)t * Bb + m0 + c) * Ii + 8 * g;
    const short* ah = RH + (size_t)(m0 + c) * Hh + 8 * g;
    const short* bw = Wc2T + (size_t)(n0 + c) * 768 + 8 * g;
    f32x4 acc[4];
    #pragma unroll
    for (int f = 0; f < 4; ++f) acc[f] = (f32x4){0.f, 0.f, 0.f, 0.f};
    #pragma unroll
    for (int k0 = 0; k0 < 128; k0 += 32) {
        const short8 a = *(const short8*)(ax + k0);
        #pragma unroll
        for (int fn = 0; fn < 4; ++fn) {
            const short8 b = *(const short8*)(bw + (size_t)fn * 16 * 768 + k0);
            acc[fn] = mfma_bf16(a, b, acc[fn]);
        }
    }
    #pragma unroll
    for (int k0 = 0; k0 < 128; k0 += 32) {
        const short8 a = *(const short8*)(am + k0);
        #pragma unroll
        for (int fn = 0; fn < 4; ++fn) {
            const short8 b = *(const short8*)(bw + (size_t)fn * 16 * 768 + 128 + k0);
            acc[fn] = mfma_bf16(a, b, acc[fn]);
        }
    }
    #pragma unroll
    for (int k0 = 0; k0 < 512; k0 += 32) {
        const short8 a = *(const short8*)(ah + k0);
        #pragma unroll
        for (int fn = 0; fn < 4; ++fn) {
            const short8 b = *(const short8*)(bw + (size_t)fn * 16 * 768 + 256 + k0);
            acc[fn] = mfma_bf16(a, b, acc[fn]);
        }
    }
    #pragma unroll
    for (int fn = 0; fn < 4; ++fn) {
        const int n = n0 + fn * 16 + c;
        const float bs = b_h[n];
        float sp = 0.f, sq = 0.f;
        #pragma unroll
        for (int j = 0; j < 4; ++j) {
            const int m = m0 + 4 * g + j;
            const float pre = acc[fn][j] + bs;
            const float z = Zbuf[(size_t)m * Hh + n];
            const float hp = bf2f(Hp[(size_t)m * Hh + n]);
            const float hr = (1.f - z) * hp + z * tanhf(pre);
            Hraw[(size_t)m * Hh + n] = hr;
            sp += hr; sq += hr * hr;
        }
        sp += __shfl_xor(sp, 16); sp += __shfl_xor(sp, 32);
        sq += __shfl_xor(sq, 16); sq += __shfl_xor(sq, 32);
        if (lane < 16) {
            atomicAdd(&Ssum[n], sp);
            atomicAdd(&Ssq[n], sq);
        }
    }
}

// ---------------------------------------------------------------------------
// K4: BN + write hs + y ; build next step's A operand Hp = bf16(Gh[t+1]*h)
// ---------------------------------------------------------------------------
__global__ __launch_bounds__(512) void bn_y_kernel(
    const float* __restrict__ Hraw, const float* __restrict__ Ssum, const float* __restrict__ Ssq,
    const float* __restrict__ gam, const float* __restrict__ bet,
    const float* __restrict__ Why, const float* __restrict__ bhy,
    const short* __restrict__ GhNext, short* __restrict__ Hp,
    float* __restrict__ out_hs, float* __restrict__ out_ys, int t, int last)
{
    const int b = blockIdx.x, n = threadIdx.x;
    const float mu = Ssum[n] * (1.f / Bb);
    const float var = fmaxf(Ssq[n] * (1.f / Bb) - mu * mu, 0.f);
    const float rstd = rsqrtf(var + EPS_BN);
    const float hr = Hraw[(size_t)b * Hh + n];
    const float ho = gam[n] * (hr - mu) * rstd + bet[n];
    out_hs[((size_t)b * Tt + t) * Hh + n] = ho;
    if (!last) {
        const float gh = bf2f(GhNext[(size_t)b * Hh + n]);
        Hp[(size_t)b * Hh + n] = f2bf(gh * ho);
    }
    __shared__ float red0[512], red1[512];
    red0[n] = ho * Why[(size_t)n * 2 + 0];
    red1[n] = ho * Why[(size_t)n * 2 + 1];
    __syncthreads();
    for (int s = 256; s > 0; s >>= 1) {
        if (n < s) { red0[n] += red0[n + s]; red1[n] += red1[n + s]; }
        __syncthreads();
    }
    if (n == 0) {
        out_ys[((size_t)b * Tt + t) * Oo + 0] = softplusf_(red0[0] + bhy[0]);
        out_ys[((size_t)b * Tt + t) * Oo + 1] = softplusf_(red1[0] + bhy[1]);
    }
}

// ---------------------------------------------------------------------------
static inline char* align_up(char* p, size_t a) {
    return (char*)(((uintptr_t)p + a - 1) & ~(uintptr_t)(a - 1));
}

extern "C" void kernel_launch(void* const* d_in, const int* in_sizes, int n_in,
                              void* d_out, int out_size, void* d_ws, size_t ws_size,
                              hipStream_t stream)
{
    const float* input  = (const float*)d_in[0];
    const float* xmean  = (const float*)d_in[1];
    const float* W_dg_x = (const float*)d_in[2];
    const float* b_dg_x = (const float*)d_in[3];
    const float* W_dg_h = (const float*)d_in[4];
    const float* b_dg_h = (const float*)d_in[5];
    const float* W_xz   = (const float*)d_in[6];
    const float* W_hz   = (const float*)d_in[7];
    const float* W_mz   = (const float*)d_in[8];
    const float* b_z    = (const float*)d_in[9];
    const float* W_xr   = (const float*)d_in[10];
    const float* W_hr   = (const float*)d_in[11];
    const float* W_mr   = (const float*)d_in[12];
    const float* b_r    = (const float*)d_in[13];
    const float* W_xh   = (const float*)d_in[14];
    const float* W_hh   = (const float*)d_in[15];
    const float* W_mh   = (const float*)d_in[16];
    const float* b_h    = (const float*)d_in[17];
    const float* W_hy   = (const float*)d_in[18];
    const float* b_hy   = (const float*)d_in[19];
    const float* bn_g   = (const float*)d_in[20];
    const float* bn_b   = (const float*)d_in[21];

    float* out_ys = (float*)d_out;
    float* out_hs = out_ys + (size_t)Bb * Tt * Oo;

    char* p = (char*)d_ws;
    float* Xall = (float*)p;            p += (size_t)TBr * Ii * 4;
    short* Mall = (short*)p;            p += (size_t)TBr * Ii * 2;
    short* Dall = (short*)p;            p += (size_t)TBr * Ii * 2;
    short* Gxb  = (short*)p;            p += (size_t)TBr * Ii * 2;
    short* Ghb  = (short*)p;            p += (size_t)TBr * Hh * 2;
    short* Xe   = (short*)p;            p += (size_t)TBr * Ii * 2;
    short* Wc1T = (short*)p;            p += (size_t)1024 * 768 * 2;
    short* Wc2T = (short*)p;            p += (size_t)512 * 768 * 2;
    short* WdgxT= (short*)p;            p += (size_t)128 * 128 * 2;
    short* WdghT= (short*)p;            p += (size_t)512 * 128 * 2;
    float* bias1= (float*)p;            p += 1024 * 4;
    float* Zbuf = (float*)p;            p += (size_t)Bb * Hh * 4;
    short* RH   = (short*)p;            p += (size_t)Bb * Hh * 2;
    short* Hp   = (short*)p;            p += (size_t)Bb * Hh * 2;
    float* Hraw = (float*)p;            p += (size_t)Bb * Hh * 4;
    float* Ssum = (float*)p;            p += Hh * 4;
    float* Ssq  = (float*)p;            p += Hh * 4;

    // initial hidden state: Hp = gammah*h0 = 0
    hipMemsetAsync(Hp, 0, (size_t)Bb * Hh * 2, stream);

    repack_kernel<<<dim3(Tt / 32, Ii / 32, Bb * 3), dim3(32, 32), 0, stream>>>(input, Xall, Mall, Dall);

    {
        const int total = 1024 * 768 + 512 * 768 + 128 * 128 + 512 * 128 + 1024;
        pack_weights_kernel<<<(total + 255) / 256, 256, 0, stream>>>(
            W_dg_x, W_dg_h,
            W_xz, W_hz, W_mz, b_z,
            W_xr, W_hr, W_mr, b_r,
            W_xh, W_hh, W_mh,
            Wc1T, Wc2T, WdgxT, WdghT, bias1);
    }

    // Gx = exp(-relu(D @ Wdgx + b)), Gh = exp(-relu(D @ Wdgh + b))
    gdecay_kernel<<<dim3(TBr / 32, Ii / 64), 64, 0, stream>>>(Dall, WdgxT, b_dg_x, Gxb, Ii);
    gdecay_kernel<<<dim3(TBr / 32, Hh / 64), 64, 0, stream>>>(Dall, WdghT, b_dg_h, Ghb, Hh);

    xeff_scan_kernel<<<(Bb * Ii) / 256, 256, 0, stream>>>(Xall, Mall, Gxb, xmean, Xe);

    for (int t = 0; t < Tt; ++t) {
        step_zr_kernel<<<dim3(Bb / 16, 1024 / 64), 64, 0, stream>>>(
            Xe, Mall, Hp, Wc1T, bias1, Zbuf, RH, Ssum, Ssq, t);
        step_h_kernel<<<dim3(Bb / 16, Hh / 64), 64, 0, stream>>>(
            Xe, Mall, RH, Hp, Wc2T, b_h, Zbuf, Hraw, Ssum, Ssq, t);
        const int last = (t == Tt - 1);
        const short* ghn = Ghb + (size_t)(last ? t : (t + 1)) * Bb * Hh;
        bn_y_kernel<<<Bb, Hh, 0, stream>>>(Hraw, Ssum, Ssq, bn_g, bn_b,
                                           W_hy, b_hy, ghn, Hp,
                                           out_hs, out_ys, t, last);
    }
}